// Round 1
// baseline (318.607 us; speedup 1.0000x reference)
//
#include <hip/hip_runtime.h>

#define BATCH    8
#define T_LEN    4096
#define D_DIM    128
#define H_HEADS  4
#define O_DIM    32
#define E_EDGES  65536
#define N_NODES  (BATCH * T_LEN)      // 32768
#define EB       (BATCH * E_EDGES)    // 524288 tiled edges
#define ET       (EB + N_NODES)       // 557056 incl. self loops
#define NEG_SLOPE 0.2f

// ---------------------------------------------------------------------------
// Probe: is edge_index stored as int64 (viewed as int32 pairs) or int32?
// For int64 little-endian with values in [0,4096), every odd int32 word is 0.
// For genuine int32 data, 64 consecutive odd words all being zero has
// probability (1/4096)^64 ~ 0.
// ---------------------------------------------------------------------------
__global__ void probe_kernel(const int* __restrict__ ei, int* __restrict__ flag) {
    if (blockIdx.x == 0 && threadIdx.x == 0) {
        int is64 = 1;
        for (int j = 0; j < 64; ++j) {
            if (ei[2 * j + 1] != 0) { is64 = 0; break; }
        }
        *flag = is64;   // 1 -> int64 layout (shift indices by 1), 0 -> int32
    }
}

// ---------------------------------------------------------------------------
// GEMM h = X*W  (N x 128) = (N x 128)(128 x 128), fp32 vector ALU.
// Fused epilogue: a_src[n][h] = sum_o h[n][h][o]*att_src[h][o], same for dst.
// Block: 256 threads, 32 rows. LDS: W 64KB + X 16KB + att 1KB.
// ---------------------------------------------------------------------------
__launch_bounds__(256)
__global__ void gemm_att_kernel(const float* __restrict__ x,
                                const float* __restrict__ W,
                                const float* __restrict__ attS,
                                const float* __restrict__ attD,
                                float* __restrict__ h,
                                float* __restrict__ aS,
                                float* __restrict__ aD) {
    __shared__ float Wl[128][128];
    __shared__ float Xl[32][128];
    __shared__ float sAS[128];
    __shared__ float sAD[128];

    const int tid  = threadIdx.x;
    const int row0 = blockIdx.x * 32;

    // stage W (4096 float4s)
    const float4* W4  = (const float4*)W;
    float4*       Wl4 = (float4*)&Wl[0][0];
    #pragma unroll
    for (int i = 0; i < 16; ++i)
        Wl4[tid + 256 * i] = W4[tid + 256 * i];

    // stage 32 rows of X (1024 float4s)
    const float4* X4  = (const float4*)(x + (size_t)row0 * 128);
    float4*       Xl4 = (float4*)&Xl[0][0];
    #pragma unroll
    for (int i = 0; i < 4; ++i)
        Xl4[tid + 256 * i] = X4[tid + 256 * i];

    if (tid < 128) { sAS[tid] = attS[tid]; sAD[tid] = attD[tid]; }
    __syncthreads();

    const int r  = tid >> 3;          // 0..31 row within tile
    const int cb = (tid & 7) * 16;    // 16 contiguous output cols

    float acc[16];
    #pragma unroll
    for (int i = 0; i < 16; ++i) acc[i] = 0.f;

    for (int k = 0; k < 128; ++k) {
        const float  xv = Xl[r][k];
        const float4 w0 = *(const float4*)&Wl[k][cb +  0];
        const float4 w1 = *(const float4*)&Wl[k][cb +  4];
        const float4 w2 = *(const float4*)&Wl[k][cb +  8];
        const float4 w3 = *(const float4*)&Wl[k][cb + 12];
        acc[ 0] += xv * w0.x; acc[ 1] += xv * w0.y; acc[ 2] += xv * w0.z; acc[ 3] += xv * w0.w;
        acc[ 4] += xv * w1.x; acc[ 5] += xv * w1.y; acc[ 6] += xv * w1.z; acc[ 7] += xv * w1.w;
        acc[ 8] += xv * w2.x; acc[ 9] += xv * w2.y; acc[10] += xv * w2.z; acc[11] += xv * w2.w;
        acc[12] += xv * w3.x; acc[13] += xv * w3.y; acc[14] += xv * w3.z; acc[15] += xv * w3.w;
    }

    // store h (coalesced float4)
    const int row = row0 + r;
    float4* hp = (float4*)(h + (size_t)row * 128 + cb);
    hp[0] = make_float4(acc[0],  acc[1],  acc[2],  acc[3]);
    hp[1] = make_float4(acc[4],  acc[5],  acc[6],  acc[7]);
    hp[2] = make_float4(acc[8],  acc[9],  acc[10], acc[11]);
    hp[3] = make_float4(acc[12], acc[13], acc[14], acc[15]);

    // fused attention logits: this thread holds 16 of the 32 o's of head cb>>5
    float ps = 0.f, pd = 0.f;
    #pragma unroll
    for (int i = 0; i < 16; ++i) {
        ps += acc[i] * sAS[cb + i];
        pd += acc[i] * sAD[cb + i];
    }
    // partner thread (tid^1) holds the other 16 o's of the same head
    ps += __shfl_down(ps, 1);
    pd += __shfl_down(pd, 1);
    if ((tid & 1) == 0) {
        const int hh = cb >> 5;       // tid even -> cb in {0,32,64,96}
        aS[row * 4 + hh] = ps;
        aD[row * 4 + hh] = pd;
    }
}

// ---------------------------------------------------------------------------
// Edge pass: 32 lanes per edge. Computes w[h] = exp(leaky_relu(aS[s]+aD[d]))
// (softmax max-shift skipped: logits are O(±4), mathematically identical),
// atomically accumulates denom[d][h] and acc[d][c] += w[h]*hfeat[s][c].
// ---------------------------------------------------------------------------
__launch_bounds__(256)
__global__ void edge_kernel(const int* __restrict__ ei,
                            const int* __restrict__ flag,
                            const float* __restrict__ h,
                            const float* __restrict__ aS,
                            const float* __restrict__ aD,
                            float* __restrict__ acc,     // d_out, pre-zeroed
                            float* __restrict__ denom) { // pre-zeroed
    const int gid  = blockIdx.x * 256 + threadIdx.x;
    const int e    = gid >> 5;
    const int lane = threadIdx.x & 31;
    if (e >= ET) return;

    int s, d;
    if (e < EB) {
        const int b  = e >> 16;       // e / E_EDGES
        const int j  = e & 65535;
        const int sh = *flag;         // 1 if int64 layout
        s = ei[j << sh]                  + b * T_LEN;
        d = ei[(E_EDGES + j) << sh]      + b * T_LEN;
    } else {
        s = d = e - EB;               // self loop
    }

    const float4 as4 = *(const float4*)(aS + (size_t)s * 4);
    const float4 ad4 = *(const float4*)(aD + (size_t)d * 4);

    float l0 = as4.x + ad4.x; l0 = (l0 > 0.f) ? l0 : NEG_SLOPE * l0;
    float l1 = as4.y + ad4.y; l1 = (l1 > 0.f) ? l1 : NEG_SLOPE * l1;
    float l2 = as4.z + ad4.z; l2 = (l2 > 0.f) ? l2 : NEG_SLOPE * l2;
    float l3 = as4.w + ad4.w; l3 = (l3 > 0.f) ? l3 : NEG_SLOPE * l3;
    const float w0 = __expf(l0);
    const float w1 = __expf(l1);
    const float w2 = __expf(l2);
    const float w3 = __expf(l3);

    if (lane < 4) {
        const float wl = (lane == 0) ? w0 : (lane == 1) ? w1 : (lane == 2) ? w2 : w3;
        atomicAdd(&denom[(size_t)d * 4 + lane], wl);
    }

    const float* hs = h   + (size_t)s * 128;
    float*       ap = acc + (size_t)d * 128;
    atomicAdd(&ap[  0 + lane], w0 * hs[  0 + lane]);
    atomicAdd(&ap[ 32 + lane], w1 * hs[ 32 + lane]);
    atomicAdd(&ap[ 64 + lane], w2 * hs[ 64 + lane]);
    atomicAdd(&ap[ 96 + lane], w3 * hs[ 96 + lane]);
}

// ---------------------------------------------------------------------------
// Finalize: out = acc/(denom+1e-16) + bias, in place on d_out. float4.
// ---------------------------------------------------------------------------
__launch_bounds__(256)
__global__ void finalize_kernel(float* __restrict__ out,
                                const float* __restrict__ denom,
                                const float* __restrict__ bias) {
    const int idx = blockIdx.x * 256 + threadIdx.x;   // over N*32 float4s
    if (idx >= N_NODES * 32) return;
    const int n  = idx >> 5;
    const int c4 = idx & 31;
    const int hh = c4 >> 3;
    const float dn = denom[(size_t)n * 4 + hh] + 1e-16f;
    const float inv = 1.0f / dn;
    float4 v = ((float4*)out)[idx];
    const float4 b = ((const float4*)bias)[c4];
    v.x = v.x * inv + b.x;
    v.y = v.y * inv + b.y;
    v.z = v.z * inv + b.z;
    v.w = v.w * inv + b.w;
    ((float4*)out)[idx] = v;
}

// ---------------------------------------------------------------------------
extern "C" void kernel_launch(void* const* d_in, const int* in_sizes, int n_in,
                              void* d_out, int out_size, void* d_ws, size_t ws_size,
                              hipStream_t stream) {
    const float* x    = (const float*)d_in[0];
    const int*   ei   = (const int*)  d_in[1];
    const float* W    = (const float*)d_in[2];
    const float* attS = (const float*)d_in[3];
    const float* attD = (const float*)d_in[4];
    const float* bias = (const float*)d_in[5];
    float* out = (float*)d_out;

    // workspace layout (floats)
    float* ws    = (float*)d_ws;
    float* h     = ws;                        // N*128
    float* aS    = h  + (size_t)N_NODES * 128; // N*4
    float* aD    = aS + (size_t)N_NODES * 4;   // N*4
    float* denom = aD + (size_t)N_NODES * 4;   // N*4
    int*   flag  = (int*)(denom + (size_t)N_NODES * 4);

    probe_kernel<<<1, 64, 0, stream>>>(ei, flag);

    hipMemsetAsync(out,   0, (size_t)out_size * sizeof(float), stream);
    hipMemsetAsync(denom, 0, (size_t)N_NODES * 4 * sizeof(float), stream);

    gemm_att_kernel<<<N_NODES / 32, 256, 0, stream>>>(x, W, attS, attD, h, aS, aD);

    edge_kernel<<<(ET * 32) / 256, 256, 0, stream>>>(ei, flag, h, aS, aD, out, denom);

    finalize_kernel<<<(N_NODES * 32) / 256, 256, 0, stream>>>(out, denom, bias);
}

// Round 4
// 132.869 us; speedup vs baseline: 2.3979x; 2.3979x over previous
//
#include <hip/hip_runtime.h>

#define BATCH    8
#define T_LEN    4096
#define D_DIM    128
#define H_HEADS  4
#define O_DIM    32
#define E_EDGES  65536
#define N_NODES  (BATCH * T_LEN)      // 32768
#define NEG_SLOPE 0.2f

// ---------------------------------------------------------------------------
// Probe: is edge_index stored as int64 (viewed as int32 pairs) or int32?
// ---------------------------------------------------------------------------
__global__ void probe_kernel(const int* __restrict__ ei, int* __restrict__ flag) {
    if (blockIdx.x == 0 && threadIdx.x == 0) {
        int is64 = 1;
        for (int j = 0; j < 64; ++j) {
            if (ei[2 * j + 1] != 0) { is64 = 0; break; }
        }
        *flag = is64;   // 1 -> int64 layout (shift word index by 1), 0 -> int32
    }
}

// ---------------------------------------------------------------------------
// CSR build over the BASE graph (shared across batches).
// ---------------------------------------------------------------------------
__launch_bounds__(256)
__global__ void hist_kernel(const int* __restrict__ ei, const int* __restrict__ flag,
                            int* __restrict__ deg) {
    const int j = blockIdx.x * 256 + threadIdx.x;
    if (j >= E_EDGES) return;
    const int sh = *flag;
    const int d = ei[(E_EDGES + j) << sh];
    atomicAdd(&deg[d], 1);
}

// exclusive scan of deg[4096] -> rowptr[4097], duplicate into cursor[4096]
__launch_bounds__(1024)
__global__ void scan_kernel(const int* __restrict__ deg,
                            int* __restrict__ rowptr, int* __restrict__ cursor) {
    __shared__ int sums[1024];
    const int tid = threadIdx.x;
    int v[4], s = 0;
    #pragma unroll
    for (int i = 0; i < 4; ++i) { v[i] = deg[tid * 4 + i]; s += v[i]; }
    sums[tid] = s;
    __syncthreads();
    // Hillis-Steele inclusive scan over the 1024 partials
    for (int off = 1; off < 1024; off <<= 1) {
        const int t = (tid >= off) ? sums[tid - off] : 0;
        __syncthreads();
        sums[tid] += t;
        __syncthreads();
    }
    int base = (tid > 0) ? sums[tid - 1] : 0;
    #pragma unroll
    for (int i = 0; i < 4; ++i) {
        rowptr[tid * 4 + i] = base;
        cursor[tid * 4 + i] = base;
        base += v[i];
    }
    if (tid == 1023) rowptr[4096] = sums[1023];
}

__launch_bounds__(256)
__global__ void fill_kernel(const int* __restrict__ ei, const int* __restrict__ flag,
                            int* __restrict__ cursor, int* __restrict__ col) {
    const int j = blockIdx.x * 256 + threadIdx.x;
    if (j >= E_EDGES) return;
    const int sh = *flag;
    const int s = ei[j << sh];
    const int d = ei[(E_EDGES + j) << sh];
    const int p = atomicAdd(&cursor[d], 1);
    col[p] = s;
}

// ---------------------------------------------------------------------------
// GEMM h = X*W  (N x 128) = (N x 128)(128 x 128), fp32 vector ALU.
// Fused epilogue: per-node attention logits aS/aD [N,4].
// ---------------------------------------------------------------------------
__launch_bounds__(256)
__global__ void gemm_att_kernel(const float* __restrict__ x,
                                const float* __restrict__ W,
                                const float* __restrict__ attS,
                                const float* __restrict__ attD,
                                float* __restrict__ h,
                                float* __restrict__ aS,
                                float* __restrict__ aD) {
    __shared__ float Wl[128][128];
    __shared__ float Xl[32][128];
    __shared__ float sAS[128];
    __shared__ float sAD[128];

    const int tid  = threadIdx.x;
    const int row0 = blockIdx.x * 32;

    const float4* W4  = (const float4*)W;
    float4*       Wl4 = (float4*)&Wl[0][0];
    #pragma unroll
    for (int i = 0; i < 16; ++i)
        Wl4[tid + 256 * i] = W4[tid + 256 * i];

    const float4* X4  = (const float4*)(x + (size_t)row0 * 128);
    float4*       Xl4 = (float4*)&Xl[0][0];
    #pragma unroll
    for (int i = 0; i < 4; ++i)
        Xl4[tid + 256 * i] = X4[tid + 256 * i];

    if (tid < 128) { sAS[tid] = attS[tid]; sAD[tid] = attD[tid]; }
    __syncthreads();

    const int r  = tid >> 3;          // 0..31 row within tile
    const int cb = (tid & 7) * 16;    // 16 contiguous output cols

    float acc[16];
    #pragma unroll
    for (int i = 0; i < 16; ++i) acc[i] = 0.f;

    for (int k = 0; k < 128; ++k) {
        const float  xv = Xl[r][k];
        const float4 w0 = *(const float4*)&Wl[k][cb +  0];
        const float4 w1 = *(const float4*)&Wl[k][cb +  4];
        const float4 w2 = *(const float4*)&Wl[k][cb +  8];
        const float4 w3 = *(const float4*)&Wl[k][cb + 12];
        acc[ 0] += xv * w0.x; acc[ 1] += xv * w0.y; acc[ 2] += xv * w0.z; acc[ 3] += xv * w0.w;
        acc[ 4] += xv * w1.x; acc[ 5] += xv * w1.y; acc[ 6] += xv * w1.z; acc[ 7] += xv * w1.w;
        acc[ 8] += xv * w2.x; acc[ 9] += xv * w2.y; acc[10] += xv * w2.z; acc[11] += xv * w2.w;
        acc[12] += xv * w3.x; acc[13] += xv * w3.y; acc[14] += xv * w3.z; acc[15] += xv * w3.w;
    }

    const int row = row0 + r;
    float4* hp = (float4*)(h + (size_t)row * 128 + cb);
    hp[0] = make_float4(acc[0],  acc[1],  acc[2],  acc[3]);
    hp[1] = make_float4(acc[4],  acc[5],  acc[6],  acc[7]);
    hp[2] = make_float4(acc[8],  acc[9],  acc[10], acc[11]);
    hp[3] = make_float4(acc[12], acc[13], acc[14], acc[15]);

    float ps = 0.f, pd = 0.f;
    #pragma unroll
    for (int i = 0; i < 16; ++i) {
        ps += acc[i] * sAS[cb + i];
        pd += acc[i] * sAD[cb + i];
    }
    ps += __shfl_down(ps, 1);
    pd += __shfl_down(pd, 1);
    if ((tid & 1) == 0) {
        const int hh = cb >> 5;
        aS[row * 4 + hh] = ps;
        aD[row * 4 + hh] = pd;
    }
}

// ---------------------------------------------------------------------------
// Gather-aggregate: one wave (64 lanes) per (batch,node). Lane owns 2
// channels (float2). Registers accumulate both numerator and per-head
// denominator; finalize fused. Zero atomics, output written exactly once.
// ---------------------------------------------------------------------------
__launch_bounds__(256)
__global__ void gather_kernel(const int* __restrict__ rowptr,
                              const int* __restrict__ col,
                              const float* __restrict__ h,
                              const float* __restrict__ aS,
                              const float* __restrict__ aD,
                              const float* __restrict__ bias,
                              float* __restrict__ out) {
    const int wid  = (blockIdx.x * 256 + threadIdx.x) >> 6;  // global wave id = node
    const int lane = threadIdx.x & 63;
    const int n    = wid;
    if (n >= N_NODES) return;
    const int t    = n & (T_LEN - 1);
    const int base = n - t;                  // b * T_LEN
    const int hh   = lane >> 4;              // head of channel 2*lane

    const float ad  = aD[(size_t)n * 4 + hh];
    const int   beg = rowptr[t];
    const int   end = rowptr[t + 1];

    float accx = 0.f, accy = 0.f, dsum = 0.f;

    for (int k = beg; k < end; ++k) {
        const int s = col[k] + base;
        const float as = aS[(size_t)s * 4 + hh];
        float l = as + ad;
        l = (l > 0.f) ? l : NEG_SLOPE * l;
        const float w = __expf(l);
        dsum += w;
        const float2 hv = *(const float2*)(h + (size_t)s * 128 + 2 * lane);
        accx += w * hv.x;
        accy += w * hv.y;
    }
    // self loop
    {
        const float as = aS[(size_t)n * 4 + hh];
        float l = as + ad;
        l = (l > 0.f) ? l : NEG_SLOPE * l;
        const float w = __expf(l);
        dsum += w;
        const float2 hv = *(const float2*)(h + (size_t)n * 128 + 2 * lane);
        accx += w * hv.x;
        accy += w * hv.y;
    }

    const float inv = 1.0f / (dsum + 1e-16f);
    const float2 bv = *(const float2*)(bias + 2 * lane);
    float2 o;
    o.x = accx * inv + bv.x;
    o.y = accy * inv + bv.y;
    *(float2*)(out + (size_t)n * 128 + 2 * lane) = o;
}

// ---------------------------------------------------------------------------
extern "C" void kernel_launch(void* const* d_in, const int* in_sizes, int n_in,
                              void* d_out, int out_size, void* d_ws, size_t ws_size,
                              hipStream_t stream) {
    const float* x    = (const float*)d_in[0];
    const int*   ei   = (const int*)  d_in[1];
    const float* W    = (const float*)d_in[2];
    const float* attS = (const float*)d_in[3];
    const float* attD = (const float*)d_in[4];
    const float* bias = (const float*)d_in[5];
    float* out = (float*)d_out;

    // workspace layout (4-byte units)
    float* ws     = (float*)d_ws;
    float* h      = ws;                                  // N*128
    float* aS     = h  + (size_t)N_NODES * 128;          // N*4
    float* aD     = aS + (size_t)N_NODES * 4;            // N*4
    int*   deg    = (int*)(aD + (size_t)N_NODES * 4);    // T
    int*   rowptr = deg    + T_LEN;                      // T+1
    int*   cursor = rowptr + T_LEN + 1;                  // T
    int*   col    = cursor + T_LEN;                      // E
    int*   flag   = col    + E_EDGES;                    // 1

    probe_kernel<<<1, 64, 0, stream>>>(ei, flag);

    hipMemsetAsync(deg, 0, T_LEN * sizeof(int), stream);

    // CSR build (base graph)
    hist_kernel<<<E_EDGES / 256, 256, 0, stream>>>(ei, flag, deg);
    scan_kernel<<<1, 1024, 0, stream>>>(deg, rowptr, cursor);
    fill_kernel<<<E_EDGES / 256, 256, 0, stream>>>(ei, flag, cursor, col);

    // projection + attention logits
    gemm_att_kernel<<<N_NODES / 32, 256, 0, stream>>>(x, W, attS, attD, h, aS, aD);

    // gather-aggregate with fused softmax-normalize + bias
    gather_kernel<<<(N_NODES * 64) / 256, 256, 0, stream>>>(rowptr, col, h, aS, aD, bias, out);
}

// Round 5
// 91.811 us; speedup vs baseline: 3.4703x; 1.4472x over previous
//
#include <hip/hip_runtime.h>

#define BATCH    8
#define T_LEN    4096
#define D_DIM    128
#define H_HEADS  4
#define O_DIM    32
#define E_EDGES  65536
#define N_NODES  (BATCH * T_LEN)      // 32768
#define NEG_SLOPE 0.2f

// ---------------------------------------------------------------------------
// Inline int64-vs-int32 layout detection (edge values < 4096, so int64 data
// has every odd 32-bit word zero; 64 zero odd words from int32 data has
// probability (1/4096)^64 ~ 0). Done by wave 0 of each block, LDS-broadcast.
// ---------------------------------------------------------------------------
__device__ __forceinline__ int detect_shift(const int* ei, int tidx, int* s_sh) {
    if (tidx < 64) {
        const int nz = (ei[2 * tidx + 1] != 0) ? 1 : 0;
        const unsigned long long b = __ballot(nz);
        if (tidx == 0) *s_sh = (b == 0ull) ? 1 : 0;
    }
    __syncthreads();
    return *s_sh;
}

// ---------------------------------------------------------------------------
// CSR build over the BASE graph (shared across batches).
// ---------------------------------------------------------------------------
__launch_bounds__(256)
__global__ void hist_kernel(const int* __restrict__ ei, int* __restrict__ deg) {
    __shared__ int s_sh;
    const int sh = detect_shift(ei, threadIdx.x, &s_sh);
    const int j = blockIdx.x * 256 + threadIdx.x;
    if (j >= E_EDGES) return;
    const int d = ei[(E_EDGES + j) << sh];
    atomicAdd(&deg[d], 1);
}

// exclusive scan of deg[4096] -> rowptr[4097], duplicate into cursor[4096]
__launch_bounds__(1024)
__global__ void scan_kernel(const int* __restrict__ deg,
                            int* __restrict__ rowptr, int* __restrict__ cursor) {
    __shared__ int wsum[16];
    const int tid  = threadIdx.x;
    const int w    = tid >> 6;
    const int lane = tid & 63;

    int v[4], s = 0;
    #pragma unroll
    for (int i = 0; i < 4; ++i) { v[i] = deg[tid * 4 + i]; s += v[i]; }

    // inclusive wave scan of s
    int inc = s;
    #pragma unroll
    for (int off = 1; off < 64; off <<= 1) {
        const int t = __shfl_up(inc, off);
        if (lane >= off) inc += t;
    }
    if (lane == 63) wsum[w] = inc;
    __syncthreads();
    if (w == 0) {
        const int t = (lane < 16) ? wsum[lane] : 0;
        int ti = t;
        #pragma unroll
        for (int off = 1; off < 16; off <<= 1) {
            const int u = __shfl_up(ti, off);
            if (lane >= off) ti += u;
        }
        if (lane < 16) wsum[lane] = ti - t;   // exclusive wave prefix
    }
    __syncthreads();

    int base = wsum[w] + (inc - s);           // exclusive prefix for this thread
    #pragma unroll
    for (int i = 0; i < 4; ++i) {
        rowptr[tid * 4 + i] = base;
        cursor[tid * 4 + i] = base;
        base += v[i];
    }
    if (tid == 1023) rowptr[4096] = base;
}

__launch_bounds__(256)
__global__ void fill_kernel(const int* __restrict__ ei,
                            int* __restrict__ cursor, int* __restrict__ col) {
    __shared__ int s_sh;
    const int sh = detect_shift(ei, threadIdx.x, &s_sh);
    const int j = blockIdx.x * 256 + threadIdx.x;
    if (j >= E_EDGES) return;
    const int s = ei[j << sh];
    const int d = ei[(E_EDGES + j) << sh];
    const int p = atomicAdd(&cursor[d], 1);
    col[p] = s;
}

// ---------------------------------------------------------------------------
// GEMM h = X*W (N x 128)(128 x 128), fp32 vector ALU. 1024 threads, 128 rows
// per block -> 256 blocks, 16 waves/CU (LDS 131 KB = 1 block/CU).
// Xl padded to 132 cols: bank(r,k) = (4r+k)%32 varies with r (no 8-way bank
// broadcast conflict on the Xl[r][k] column read).
// Fused epilogue: per-node attention logits aS/aD [N,4].
// ---------------------------------------------------------------------------
__launch_bounds__(1024)
__global__ void gemm_att_kernel(const float* __restrict__ x,
                                const float* __restrict__ W,
                                const float* __restrict__ attS,
                                const float* __restrict__ attD,
                                float* __restrict__ h,
                                float* __restrict__ aS,
                                float* __restrict__ aD) {
    __shared__ float Wl[128][128];
    __shared__ float Xl[128][132];
    __shared__ float sAS[128];
    __shared__ float sAD[128];

    const int tid  = threadIdx.x;
    const int row0 = blockIdx.x * 128;

    // stage W (4096 float4s)
    const float4* W4  = (const float4*)W;
    float4*       Wl4 = (float4*)&Wl[0][0];
    #pragma unroll
    for (int i = 0; i < 4; ++i)
        Wl4[tid + 1024 * i] = W4[tid + 1024 * i];

    // stage 128 rows of X into padded tile (row stride 132 floats, 16B-aligned)
    const float4* X4 = (const float4*)(x + (size_t)row0 * 128);
    #pragma unroll
    for (int i = 0; i < 4; ++i) {
        const int idx = tid + 1024 * i;
        const int row = idx >> 5;
        const int c4  = idx & 31;
        *(float4*)&Xl[row][c4 * 4] = X4[idx];
    }

    if (tid < 128) { sAS[tid] = attS[tid]; sAD[tid] = attD[tid]; }
    __syncthreads();

    const int r  = tid >> 3;          // 0..127 row within tile
    const int cb = (tid & 7) * 16;    // 16 contiguous output cols

    float acc[16];
    #pragma unroll
    for (int i = 0; i < 16; ++i) acc[i] = 0.f;

    for (int k = 0; k < 128; ++k) {
        const float  xv = Xl[r][k];
        const float4 w0 = *(const float4*)&Wl[k][cb +  0];
        const float4 w1 = *(const float4*)&Wl[k][cb +  4];
        const float4 w2 = *(const float4*)&Wl[k][cb +  8];
        const float4 w3 = *(const float4*)&Wl[k][cb + 12];
        acc[ 0] += xv * w0.x; acc[ 1] += xv * w0.y; acc[ 2] += xv * w0.z; acc[ 3] += xv * w0.w;
        acc[ 4] += xv * w1.x; acc[ 5] += xv * w1.y; acc[ 6] += xv * w1.z; acc[ 7] += xv * w1.w;
        acc[ 8] += xv * w2.x; acc[ 9] += xv * w2.y; acc[10] += xv * w2.z; acc[11] += xv * w2.w;
        acc[12] += xv * w3.x; acc[13] += xv * w3.y; acc[14] += xv * w3.z; acc[15] += xv * w3.w;
    }

    const int row = row0 + r;
    float4* hp = (float4*)(h + (size_t)row * 128 + cb);
    hp[0] = make_float4(acc[0],  acc[1],  acc[2],  acc[3]);
    hp[1] = make_float4(acc[4],  acc[5],  acc[6],  acc[7]);
    hp[2] = make_float4(acc[8],  acc[9],  acc[10], acc[11]);
    hp[3] = make_float4(acc[12], acc[13], acc[14], acc[15]);

    float ps = 0.f, pd = 0.f;
    #pragma unroll
    for (int i = 0; i < 16; ++i) {
        ps += acc[i] * sAS[cb + i];
        pd += acc[i] * sAD[cb + i];
    }
    ps += __shfl_down(ps, 1);   // partner tid^1 holds the other 16 o's of this head
    pd += __shfl_down(pd, 1);
    if ((tid & 1) == 0) {
        const int hh = cb >> 5;
        aS[row * 4 + hh] = ps;
        aD[row * 4 + hh] = pd;
    }
}

// ---------------------------------------------------------------------------
// Gather-aggregate, 4-edge ILP: one wave per (batch,node); lanes are
// 4 edge-slots x 16 channel-groups (8 channels each). Each round processes
// 4 edges concurrently; cross-slot shfl_xor reduce at the end. Zero atomics.
// ---------------------------------------------------------------------------
__launch_bounds__(256)
__global__ void gather_kernel(const int* __restrict__ rowptr,
                              const int* __restrict__ col,
                              const float* __restrict__ h,
                              const float* __restrict__ aS,
                              const float* __restrict__ aD,
                              const float* __restrict__ bias,
                              float* __restrict__ out) {
    const int n    = (blockIdx.x * 256 + threadIdx.x) >> 6;  // node = global wave id
    const int lane = threadIdx.x & 63;
    if (n >= N_NODES) return;
    const int t    = n & (T_LEN - 1);
    const int base = n - t;                  // b * T_LEN
    const int g    = lane >> 4;              // edge slot 0..3
    const int ci   = (lane & 15) * 8;        // first of 8 owned channels
    const int hh   = (lane & 15) >> 2;       // head of those channels

    const float ad  = aD[(size_t)n * 4 + hh];
    const int   beg = rowptr[t];
    const int   end = rowptr[t + 1];

    float acc[8];
    #pragma unroll
    for (int i = 0; i < 8; ++i) acc[i] = 0.f;
    float dsum = 0.f;

    for (int k = beg; k < end; k += 4) {
        const int kk = k + g;
        if (kk < end) {
            const int s = col[kk] + base;
            float l = aS[(size_t)s * 4 + hh] + ad;
            l = (l > 0.f) ? l : NEG_SLOPE * l;
            const float w = __expf(l);
            dsum += w;
            const float* hp = h + (size_t)s * 128 + ci;
            const float4 h0 = *(const float4*)(hp);
            const float4 h1 = *(const float4*)(hp + 4);
            acc[0] += w * h0.x; acc[1] += w * h0.y; acc[2] += w * h0.z; acc[3] += w * h0.w;
            acc[4] += w * h1.x; acc[5] += w * h1.y; acc[6] += w * h1.z; acc[7] += w * h1.w;
        }
    }

    // self loop (slot 0 only, so it's counted once)
    if (g == 0) {
        float l = aS[(size_t)n * 4 + hh] + ad;
        l = (l > 0.f) ? l : NEG_SLOPE * l;
        const float w = __expf(l);
        dsum += w;
        const float* hp = h + (size_t)n * 128 + ci;
        const float4 h0 = *(const float4*)(hp);
        const float4 h1 = *(const float4*)(hp + 4);
        acc[0] += w * h0.x; acc[1] += w * h0.y; acc[2] += w * h0.z; acc[3] += w * h0.w;
        acc[4] += w * h1.x; acc[5] += w * h1.y; acc[6] += w * h1.z; acc[7] += w * h1.w;
    }

    // reduce across the 4 edge slots (lanes 16 apart hold the same channels)
    #pragma unroll
    for (int i = 0; i < 8; ++i) {
        acc[i] += __shfl_xor(acc[i], 16);
        acc[i] += __shfl_xor(acc[i], 32);
    }
    dsum += __shfl_xor(dsum, 16);
    dsum += __shfl_xor(dsum, 32);

    if (lane < 16) {
        const float inv = 1.0f / (dsum + 1e-16f);
        const float4 b0 = *(const float4*)(bias + ci);
        const float4 b1 = *(const float4*)(bias + ci + 4);
        float4 o0, o1;
        o0.x = acc[0] * inv + b0.x; o0.y = acc[1] * inv + b0.y;
        o0.z = acc[2] * inv + b0.z; o0.w = acc[3] * inv + b0.w;
        o1.x = acc[4] * inv + b1.x; o1.y = acc[5] * inv + b1.y;
        o1.z = acc[6] * inv + b1.z; o1.w = acc[7] * inv + b1.w;
        float* op = out + (size_t)n * 128 + ci;
        *(float4*)(op)     = o0;
        *(float4*)(op + 4) = o1;
    }
}

// ---------------------------------------------------------------------------
extern "C" void kernel_launch(void* const* d_in, const int* in_sizes, int n_in,
                              void* d_out, int out_size, void* d_ws, size_t ws_size,
                              hipStream_t stream) {
    const float* x    = (const float*)d_in[0];
    const int*   ei   = (const int*)  d_in[1];
    const float* W    = (const float*)d_in[2];
    const float* attS = (const float*)d_in[3];
    const float* attD = (const float*)d_in[4];
    const float* bias = (const float*)d_in[5];
    float* out = (float*)d_out;

    // workspace layout (4-byte units)
    float* ws     = (float*)d_ws;
    float* h      = ws;                                  // N*128
    float* aS     = h  + (size_t)N_NODES * 128;          // N*4
    float* aD     = aS + (size_t)N_NODES * 4;            // N*4
    int*   deg    = (int*)(aD + (size_t)N_NODES * 4);    // T
    int*   rowptr = deg    + T_LEN;                      // T+1
    int*   cursor = rowptr + T_LEN + 1;                  // T
    int*   col    = cursor + T_LEN;                      // E

    hipMemsetAsync(deg, 0, T_LEN * sizeof(int), stream);

    // CSR build (base graph)
    hist_kernel<<<E_EDGES / 256, 256, 0, stream>>>(ei, deg);
    scan_kernel<<<1, 1024, 0, stream>>>(deg, rowptr, cursor);
    fill_kernel<<<E_EDGES / 256, 256, 0, stream>>>(ei, cursor, col);

    // projection + attention logits
    gemm_att_kernel<<<N_NODES / 128, 1024, 0, stream>>>(x, W, attS, attD, h, aS, aD);

    // gather-aggregate with fused softmax-normalize + bias
    gather_kernel<<<(N_NODES * 64) / 256, 256, 0, stream>>>(rowptr, col, h, aS, aD, bias, out);
}